// Round 12
// baseline (117.414 us; speedup 1.0000x reference)
//
#include <hip/hip_runtime.h>
#include <hip/hip_bf16.h>

// ChebyKANLinear: y[b,j] = sum_i sum_k T_k(tanh(x[b,i])) * C[i,j,k]
// GEMM: M=16384, N=512, K=4608 (kflat = k*512 + i), k=0 folded into S0[j].
// v11: latency-hiding via occupancy. Barrier-free v9 structure, but:
//   - 4 waves/SIMD (8-wave 512-thr blocks, 2 blocks/CU, <=128 VGPR/wave)
//   - full f16 pipeline: W2 = f16(C*256) (subnormal-safe), recurrence in
//     packed f16 (v_pk_fma_f16) with zero-copy A0/A1 ping-pong; Tk regs ARE
//     the MFMA A operand (mfma_f32_16x16x32_f16) -> no per-kstep cvt.
//     (v6's f16 failure was the parity bug, not numerics: v6/v7 absmax were
//     bit-identical. f16 quantization is 8x finer than the proven bf16.)
//   - wave tile 64x32: 8 MFMA/kstep, B-traffic 2KB/wave/kstep (L1 ~27us/CU).
//   - epilogue scales by 2^-8; acc init = S0*256.

typedef _Float16 f16x8 __attribute__((ext_vector_type(8)));
typedef float    f32x4 __attribute__((ext_vector_type(4)));

#define DIM  512
#define KDEG 9
#define NK   8               // k = 1..8 (k=0 folded into S0)
#define NIC  16
#define SLAB (4 * DIM * 8)   // 16384 f16 per (k,ic) slab of W2

// ---- pack: C[i][j][k] -> W2[(k*16+ic)][s][j][e] = f16(C*256), i=ic*32+s*8+e ----
__global__ void pack_w_kernel(const float* __restrict__ coeffs,
                              _Float16* __restrict__ W2) {
    int t  = blockIdx.x * blockDim.x + threadIdx.x;   // 32768 threads
    int j  = t & (DIM - 1);
    int s  = (t >> 9) & 3;
    int ic = t >> 11;

    f16x8 v[KDEG];
#pragma unroll
    for (int e = 0; e < 8; ++e) {
        int i = ic * 32 + s * 8 + e;
        const float* src = coeffs + ((size_t)i * DIM + j) * KDEG;
#pragma unroll
        for (int k = 0; k < KDEG; ++k)
            v[k][e] = (_Float16)(src[k] * 256.0f);
    }
#pragma unroll
    for (int k = 0; k < KDEG; ++k) {
        size_t off = (size_t)(k * 16 + ic) * SLAB + ((size_t)s * DIM + j) * 8;
        *reinterpret_cast<f16x8*>(W2 + off) = v[k];
    }
}

// ---- S0[j] = sum_i C[i][j][0] (f32, unscaled), into W2's unused k=0 slab ----
__global__ void s0_kernel(const float* __restrict__ coeffs,
                          float* __restrict__ S0) {
    const int j    = blockIdx.x;      // 512 blocks
    const int lane = threadIdx.x;     // 64
    float s = 0.0f;
#pragma unroll
    for (int i = lane; i < DIM; i += 64)
        s += coeffs[((size_t)i * DIM + j) * KDEG];
#pragma unroll
    for (int off = 32; off > 0; off >>= 1)
        s += __shfl_down(s, off, 64);
    if (lane == 0) S0[j] = s;
}

// ---------------- fused Chebyshev-basis + MFMA GEMM, barrier-free ---------------
__global__ __launch_bounds__(512, 4) void cheby_gemm_kernel(
    const float* __restrict__ x,
    const _Float16* __restrict__ W2,
    float* __restrict__ out)
{
    const int tid  = threadIdx.x;
    const int lane = tid & 63;
    const int wid  = tid >> 6;      // 0..7
    const int wr   = wid >> 2;      // 0..1  m-group (64 rows)
    const int wc   = wid & 3;       // 0..3  n-group (32 cols)
    const int l15  = lane & 15;
    const int l4   = lane >> 4;     // 0..3
    const int bm   = blockIdx.y * 128;
    const int bn   = blockIdx.x * 128;

    // B lane base: granule (l4*DIM + bn + wc*32 + nf*16 + l15), 16B each
    const _Float16* wbase = W2 + ((size_t)l4 * DIM + bn + wc * 32 + l15) * 8;

    // x rows: bm + wr*64 + mf*16 + l15; lane's 8 i's at slot l4
    const float* xr = x + (size_t)(bm + wr * 64 + l15) * DIM + l4 * 8;

    // acc init from S0 (k=0 term), pre-scaled by 256 to match W2 scaling
    const float* S0 = (const float*)W2;
    f32x4 acc[4][2];
#pragma unroll
    for (int nf = 0; nf < 2; ++nf) {
        float s0v = S0[bn + wc * 32 + nf * 16 + l15] * 256.0f;
#pragma unroll
        for (int mf = 0; mf < 4; ++mf)
#pragma unroll
            for (int r = 0; r < 4; ++r)
                acc[mf][nf][r] = s0v;
    }

    f16x8 aone;
#pragma unroll
    for (int e = 0; e < 8; ++e) aone[e] = (_Float16)1.0f;

    // B 2-set register buffer; prologue: (k=1, ic=0) -> set 0.
    // 8 ksteps/ic (even) -> parity-safe across ic boundaries (v9-proven).
    f16x8 bq[2][2];
#pragma unroll
    for (int nf = 0; nf < 2; ++nf)
        bq[0][nf] = *reinterpret_cast<const f16x8*>(
            wbase + (size_t)16 * SLAB + nf * 128);

    for (int ic = 0; ic < NIC; ++ic) {
        // ---- basis init: t = tanh(x) in f32, stored as packed f16 ----
        // A0 = T_1, A1 = T_0 = 1; ping-pong thereafter (zero copies).
        f16x8 A0[4], A1[4], t2[4];
#pragma unroll
        for (int mf = 0; mf < 4; ++mf) {
            f32x4 xa = *reinterpret_cast<const f32x4*>(xr + mf * 16 * DIM + ic * 32);
            f32x4 xb = *reinterpret_cast<const f32x4*>(xr + mf * 16 * DIM + ic * 32 + 4);
            f16x8 tf;
#pragma unroll
            for (int e = 0; e < 8; ++e) {
                float xv = (e < 4) ? xa[e] : xb[e - 4];
                float p  = __builtin_amdgcn_exp2f(xv * 2.8853900817779268f);
                tf[e] = (_Float16)(1.0f - 2.0f * __builtin_amdgcn_rcpf(p + 1.0f));
            }
            A0[mf] = tf;           // T_1
            t2[mf] = tf + tf;      // 2t (packed)
            A1[mf] = aone;         // T_0
        }

#pragma unroll
        for (int kk = 0; kk < NK; ++kk) {     // consuming k = kk+1
            const int cs = kk & 1;
            // prefetch next kstep's B into the other set (never drained)
            if ((kk < NK - 1) || (ic + 1 < NIC)) {
                const int nk  = (kk < NK - 1) ? kk + 2 : 1;     // k index 1..8
                const int nic = (kk < NK - 1) ? ic : ic + 1;
                const _Float16* np = wbase + (size_t)(nk * 16 + nic) * SLAB;
#pragma unroll
                for (int nf = 0; nf < 2; ++nf)
                    bq[cs ^ 1][nf] = *reinterpret_cast<const f16x8*>(np + nf * 128);
            }

            // 8 MFMA; A operand ping-pongs A0/A1 (T_{kk+1} lives there)
#pragma unroll
            for (int nf = 0; nf < 2; ++nf)
#pragma unroll
                for (int mf = 0; mf < 4; ++mf)
                    acc[mf][nf] = __builtin_amdgcn_mfma_f32_16x16x32_f16(
                        cs ? A1[mf] : A0[mf], bq[cs][nf], acc[mf][nf], 0, 0, 0);

            // recurrence: other <- 2t * cur - other  (4 v_pk_fma_f16 per mf)
            if (kk < NK - 1) {
#pragma unroll
                for (int mf = 0; mf < 4; ++mf) {
                    if (cs) A0[mf] = t2[mf] * A1[mf] - A0[mf];
                    else    A1[mf] = t2[mf] * A0[mf] - A1[mf];
                }
            }
        }
    }

    // ---- epilogue: C/D layout col=lane&15, row=(lane>>4)*4+r ; undo x256 ----
#pragma unroll
    for (int mf = 0; mf < 4; ++mf)
#pragma unroll
        for (int r = 0; r < 4; ++r) {
            const int row = bm + wr * 64 + mf * 16 + l4 * 4 + r;
            float* orow = out + (size_t)row * DIM + bn + wc * 32 + l15;
#pragma unroll
            for (int nf = 0; nf < 2; ++nf)
                orow[nf * 16] = acc[mf][nf][r] * 0.00390625f;
        }
}

extern "C" void kernel_launch(void* const* d_in, const int* in_sizes, int n_in,
                              void* d_out, int out_size, void* d_ws, size_t ws_size,
                              hipStream_t stream) {
    const float* x      = (const float*)d_in[0];   // (16384, 512)
    const float* coeffs = (const float*)d_in[1];   // (512, 512, 9)
    float* out          = (float*)d_out;           // (16384, 512)
    _Float16* W2        = (_Float16*)d_ws;         // 144*16384 f16 = 4.7MB

    pack_w_kernel<<<(DIM * 64) / 256, 256, 0, stream>>>(coeffs, W2);
    // S0 (f32) into the GEMM-unused k=0 slab region of W2
    s0_kernel<<<DIM, 64, 0, stream>>>(coeffs, (float*)W2);

    // grid = (N/128, M/128) = (4, 128) = 512 blocks of 512 thr
    //      = 2 blocks/CU = 16 waves/CU = 4 waves/SIMD
    cheby_gemm_kernel<<<dim3(4, 128), 512, 0, stream>>>(x, W2, out);
}

// Round 13
// 103.448 us; speedup vs baseline: 1.1350x; 1.1350x over previous
//
#include <hip/hip_runtime.h>
#include <hip/hip_bf16.h>

// ChebyKANLinear: y[b,j] = sum_i sum_k T_k(tanh(x[b,i])) * C[i,j,k]
// GEMM: M=16384, N=512, K=4608 (kflat = k*512 + i), k=0 folded into S0[j].
// v12: dup=1. Block = 8 waves (1m x 8n), BM=64, BN=512 (ALL cols) -> the
//   Chebyshev basis is computed exactly ONCE chip-wide (produce phase:
//   512 thr x 4 vals -> 32KB LDS A-tile, v10's verified XOR-slot conflict-free
//   layout), and x is fetched exactly once. Consume: A from LDS (67 B/cyc
//   < 85 LDS ceiling), B reg-2-set from L2-resident W2 (53 B/cyc < 64 L1),
//   16 MFMA/kstep/wave. Raw s_barrier + lgkmcnt(0) only; B never drained.
//   grid 256 = 1 block/CU, 2 waves/SIMD, ~150 VGPR.

typedef __bf16 bf16x8 __attribute__((ext_vector_type(8)));
typedef __bf16 bf16x4 __attribute__((ext_vector_type(4)));
typedef float  f32x4  __attribute__((ext_vector_type(4)));

#define DIM  512
#define KDEG 9
#define NK   8               // k = 1..8 (k=0 folded into S0)
#define NIC  16
#define SLAB (4 * DIM * 8)   // 16384 bf16 per (k,ic) slab of W2

// ---- pack: C[i][j][k] -> W2[(k*16+ic)][s][j][e] (bf16), i = ic*32 + s*8 + e ----
__global__ void pack_w_kernel(const float* __restrict__ coeffs,
                              __bf16* __restrict__ W2) {
    int t  = blockIdx.x * blockDim.x + threadIdx.x;   // 32768 threads
    int j  = t & (DIM - 1);
    int s  = (t >> 9) & 3;
    int ic = t >> 11;

    bf16x8 v[KDEG];
#pragma unroll
    for (int e = 0; e < 8; ++e) {
        int i = ic * 32 + s * 8 + e;
        const float* src = coeffs + ((size_t)i * DIM + j) * KDEG;
#pragma unroll
        for (int k = 0; k < KDEG; ++k)
            v[k][e] = (__bf16)src[k];
    }
#pragma unroll
    for (int k = 0; k < KDEG; ++k) {
        size_t off = (size_t)(k * 16 + ic) * SLAB + ((size_t)s * DIM + j) * 8;
        *reinterpret_cast<bf16x8*>(W2 + off) = v[k];
    }
}

// ---- S0[j] = sum_i C[i][j][0] (f32) into W2's k=0 slab (GEMM never reads it) ----
__global__ void s0_kernel(const float* __restrict__ coeffs,
                          float* __restrict__ S0) {
    const int j    = blockIdx.x;      // 512 blocks
    const int lane = threadIdx.x;     // 64
    float s = 0.0f;
#pragma unroll
    for (int i = lane; i < DIM; i += 64)
        s += coeffs[((size_t)i * DIM + j) * KDEG];
#pragma unroll
    for (int off = 32; off > 0; off >>= 1)
        s += __shfl_down(s, off, 64);
    if (lane == 0) S0[j] = s;
}

// ---------------- fused: produce(basis->LDS, once) / consume(MFMA) --------------
__global__ __launch_bounds__(512, 2) void cheby_gemm_kernel(
    const float* __restrict__ x,
    const __bf16* __restrict__ W2,
    float* __restrict__ out)
{
    // A-tile: [kk][row(64)][slot(4)][8] bf16 = 32KB; slot stored XOR-swizzled
    __shared__ __bf16 A_lds[NK][64][4][8];

    const int tid  = threadIdx.x;
    const int lane = tid & 63;
    const int wid  = tid >> 6;      // 0..7 = n-group (64 cols each)
    const int l15  = lane & 15;
    const int l4   = lane >> 4;     // 0..3
    const int bm   = blockIdx.x * 64;

    // ---- producer mapping: thread owns 4 consecutive i of one row ----
    const int prow  = tid >> 3;           // 0..63
    const int pi4   = (tid & 7) * 4;      // 0,4,...,28
    const int pslot = pi4 >> 3;           // 0..3
    const int phalf = (pi4 >> 2) & 1;     // 8B half within slot
    const int rsw   = (prow >> 1) & 3;    // row-pair slot swizzle
    __bf16* wp = &A_lds[0][prow][pslot ^ rsw][phalf * 4];
    const float* xp = x + (size_t)(bm + prow) * DIM + pi4;

    // ---- consumer A read base: row = mf*16 + l15, logical slot l4 ----
    const __bf16* abase = &A_lds[0][l15][l4 ^ ((l15 >> 1) & 3)][0];

    // ---- B lane base: granule (l4*DIM + wid*64 + nf*16 + l15), 16B each ----
    const __bf16* wbase = W2 + ((size_t)l4 * DIM + wid * 64 + l15) * 8;

    // acc init from S0 (the k=0 term)
    const float* S0 = (const float*)W2;
    f32x4 acc[4][4];
#pragma unroll
    for (int nf = 0; nf < 4; ++nf) {
        float s0v = S0[wid * 64 + nf * 16 + l15];
#pragma unroll
        for (int mf = 0; mf < 4; ++mf)
#pragma unroll
            for (int r = 0; r < 4; ++r)
                acc[mf][nf][r] = s0v;
    }

    // B 2-set register buffer; 8 even ksteps/ic -> parity-safe across ic.
    bf16x8 bq[2][4];
#pragma unroll
    for (int nf = 0; nf < 4; ++nf)
        bq[0][nf] = *reinterpret_cast<const bf16x8*>(
            wbase + (size_t)16 * SLAB + nf * 128);   // (k=1, ic=0)

    // producer x for ic=0
    f32x4 xq = *reinterpret_cast<const f32x4*>(xp);

    for (int ic = 0; ic < NIC; ++ic) {
        // ================= produce: basis -> LDS (4 vals/thread) =================
        float Tk[4], Tm[4], t2[4];
#pragma unroll
        for (int e = 0; e < 4; ++e) {
            float p = __builtin_amdgcn_exp2f(xq[e] * 2.8853900817779268f);
            float t = 1.0f - 2.0f * __builtin_amdgcn_rcpf(p + 1.0f);
            Tk[e] = t;          // T_1
            t2[e] = t + t;
            Tm[e] = 1.0f;       // T_0
        }
#pragma unroll
        for (int kk = 0; kk < NK; ++kk) {     // stores T_{kk+1}
            bf16x4 v;
#pragma unroll
            for (int e = 0; e < 4; ++e) v[e] = (__bf16)Tk[e];
            *reinterpret_cast<bf16x4*>(wp + kk * 2048) = v;   // ds_write_b64
            if (kk < NK - 1) {
#pragma unroll
                for (int e = 0; e < 4; ++e) {
                    float Tn = __builtin_fmaf(t2[e], Tk[e], -Tm[e]);
                    Tm[e] = Tk[e];
                    Tk[e] = Tn;
                }
            }
        }
        // prefetch next ic's x (in flight across the whole consume phase)
        if (ic + 1 < NIC)
            xq = *reinterpret_cast<const f32x4*>(xp + (ic + 1) * 32);

        asm volatile("s_waitcnt lgkmcnt(0)" ::: "memory");
        __builtin_amdgcn_s_barrier();

        // ================= consume: 8 ksteps (A from LDS, B from regs) ==========
#pragma unroll
        for (int k = 1; k <= NK; ++k) {
            const int cs = (k - 1) & 1;
            // prefetch next kstep's B into the other set (never drained)
            if ((k < NK) || (ic + 1 < NIC)) {
                const int nk  = (k < NK) ? k + 1 : 1;
                const int nic = (k < NK) ? ic : ic + 1;
                const __bf16* np = wbase + (size_t)(nk * 16 + nic) * SLAB;
#pragma unroll
                for (int nf = 0; nf < 4; ++nf)
                    bq[cs ^ 1][nf] = *reinterpret_cast<const bf16x8*>(np + nf * 128);
            }

            // A frags from LDS (conflict-free swizzled reads)
            bf16x8 af[4];
#pragma unroll
            for (int mf = 0; mf < 4; ++mf)
                af[mf] = *reinterpret_cast<const bf16x8*>(
                    abase + (k - 1) * 2048 + mf * 512);

            // 16 MFMA
#pragma unroll
            for (int nf = 0; nf < 4; ++nf)
#pragma unroll
                for (int mf = 0; mf < 4; ++mf)
                    acc[mf][nf] = __builtin_amdgcn_mfma_f32_16x16x32_bf16(
                        af[mf], bq[cs][nf], acc[mf][nf], 0, 0, 0);
        }
        __builtin_amdgcn_s_barrier();   // all reads done -> next produce may overwrite
    }

    // ---- epilogue: C/D layout col=lane&15, row=(lane>>4)*4+r ----
#pragma unroll
    for (int mf = 0; mf < 4; ++mf)
#pragma unroll
        for (int r = 0; r < 4; ++r) {
            const int row = bm + mf * 16 + l4 * 4 + r;
            float* orow = out + (size_t)row * DIM + wid * 64 + l15;
#pragma unroll
            for (int nf = 0; nf < 4; ++nf)
                orow[nf * 16] = acc[mf][nf][r];
        }
}

extern "C" void kernel_launch(void* const* d_in, const int* in_sizes, int n_in,
                              void* d_out, int out_size, void* d_ws, size_t ws_size,
                              hipStream_t stream) {
    const float* x      = (const float*)d_in[0];   // (16384, 512)
    const float* coeffs = (const float*)d_in[1];   // (512, 512, 9)
    float* out          = (float*)d_out;           // (16384, 512)
    __bf16* W2          = (__bf16*)d_ws;           // 144*16384 bf16 = 4.7MB

    pack_w_kernel<<<(DIM * 64) / 256, 256, 0, stream>>>(coeffs, W2);
    // S0 (f32) into the GEMM-unused k=0 slab region of W2
    s0_kernel<<<DIM, 64, 0, stream>>>(coeffs, (float*)W2);

    // grid = M/64 = 256 blocks of 512 thr = 1 block/CU, 2 waves/SIMD.
    // Each block owns ALL 512 output cols -> basis computed once chip-wide,
    // x fetched once.
    cheby_gemm_kernel<<<256, 512, 0, stream>>>(x, W2, out);
}

// Round 14
// 92.849 us; speedup vs baseline: 1.2646x; 1.1142x over previous
//
#include <hip/hip_runtime.h>
#include <hip/hip_bf16.h>

// ChebyKANLinear: y[b,j] = sum_i sum_k T_k(tanh(x[b,i])) * C[i,j,k]
// GEMM: M=16384, N=512, K=4608 (kflat = k*512 + i), k=0 folded into S0[j].
// v13 = v12 (dup=1: block owns all 512 cols, basis computed once chip-wide)
//   + two latency fixes the counters demanded:
//   (1) B prefetch depth 3 ksteps (4 register sets, ~930 cyc cover vs L2/L3
//       latency; W2 4.7MB > 4MB/XCD L2 so some L3 service is unavoidable).
//   (2) produce(ic+1) interleaved INTO consume(ic) with double-buffered
//       A-LDS (2x32KB): one recurrence step + one ds_write_b64 per kstep
//       hides under 16 MFMAs; barriers drop to 1/ic. ic-unroll x2 keeps the
//       LDS buffer index compile-time.

typedef __bf16 bf16x8 __attribute__((ext_vector_type(8)));
typedef __bf16 bf16x4 __attribute__((ext_vector_type(4)));
typedef float  f32x4  __attribute__((ext_vector_type(4)));

#define DIM  512
#define KDEG 9
#define NK   8               // k = 1..8 (k=0 folded into S0)
#define NIC  16
#define SLAB (4 * DIM * 8)   // 16384 bf16 per (k,ic) slab of W2

// ---- pack: C[i][j][k] -> W2[(k*16+ic)][s][j][e] (bf16), i = ic*32 + s*8 + e ----
__global__ void pack_w_kernel(const float* __restrict__ coeffs,
                              __bf16* __restrict__ W2) {
    int t  = blockIdx.x * blockDim.x + threadIdx.x;   // 32768 threads
    int j  = t & (DIM - 1);
    int s  = (t >> 9) & 3;
    int ic = t >> 11;

    bf16x8 v[KDEG];
#pragma unroll
    for (int e = 0; e < 8; ++e) {
        int i = ic * 32 + s * 8 + e;
        const float* src = coeffs + ((size_t)i * DIM + j) * KDEG;
#pragma unroll
        for (int k = 0; k < KDEG; ++k)
            v[k][e] = (__bf16)src[k];
    }
#pragma unroll
    for (int k = 0; k < KDEG; ++k) {
        size_t off = (size_t)(k * 16 + ic) * SLAB + ((size_t)s * DIM + j) * 8;
        *reinterpret_cast<bf16x8*>(W2 + off) = v[k];
    }
}

// ---- S0[j] = sum_i C[i][j][0] (f32) into W2's k=0 slab (GEMM never reads it) ----
__global__ void s0_kernel(const float* __restrict__ coeffs,
                          float* __restrict__ S0) {
    const int j    = blockIdx.x;      // 512 blocks
    const int lane = threadIdx.x;     // 64
    float s = 0.0f;
#pragma unroll
    for (int i = lane; i < DIM; i += 64)
        s += coeffs[((size_t)i * DIM + j) * KDEG];
#pragma unroll
    for (int off = 32; off > 0; off >>= 1)
        s += __shfl_down(s, off, 64);
    if (lane == 0) S0[j] = s;
}

// ---------------- fused GEMM: consume(ic) with produce(ic+1) interleaved --------
__global__ __launch_bounds__(512, 2) void cheby_gemm_kernel(
    const float* __restrict__ x,
    const __bf16* __restrict__ W2,
    float* __restrict__ out)
{
    // double-buffered A-tile: [buf][kk][row(64)][slot(4)][8] bf16, 2 x 32KB
    __shared__ __bf16 A_lds[2][NK][64][4][8];

    const int tid  = threadIdx.x;
    const int lane = tid & 63;
    const int wid  = tid >> 6;      // 0..7 = n-group (64 cols each)
    const int l15  = lane & 15;
    const int l4   = lane >> 4;     // 0..3
    const int bm   = blockIdx.x * 64;

    // ---- producer mapping: thread owns 4 consecutive i of one row ----
    const int prow  = tid >> 3;           // 0..63
    const int pi4   = (tid & 7) * 4;      // 0,4,...,28
    const int pslot = pi4 >> 3;           // 0..3
    const int phalf = (pi4 >> 2) & 1;     // 8B half within slot
    const int rsw   = (prow >> 1) & 3;    // row-pair slot swizzle
    __bf16* wp = &A_lds[0][0][prow][pslot ^ rsw][phalf * 4];
    const float* xp = x + (size_t)(bm + prow) * DIM + pi4;

    // ---- consumer A read base: row = mf*16 + l15 (swizzle dep. only on l15) ----
    const __bf16* abase = &A_lds[0][0][l15][l4 ^ ((l15 >> 1) & 3)][0];

    // ---- B lane base: granule (l4*DIM + wid*64 + nf*16 + l15), 16B each ----
    const __bf16* wbase = W2 + ((size_t)l4 * DIM + wid * 64 + l15) * 8;

    // acc init from S0 (the k=0 term)
    const float* S0 = (const float*)W2;
    f32x4 acc[4][4];
#pragma unroll
    for (int nf = 0; nf < 4; ++nf) {
        float s0v = S0[wid * 64 + nf * 16 + l15];
#pragma unroll
        for (int mf = 0; mf < 4; ++mf)
#pragma unroll
            for (int r = 0; r < 4; ++r)
                acc[mf][nf][r] = s0v;
    }

    // ================= prologue =================
    // x(0); produce ic=0 into buf 0 (serial, once)
    f32x4 xq = *reinterpret_cast<const f32x4*>(xp);
    {
        float Tk[4], Tm[4], t2[4];
#pragma unroll
        for (int e = 0; e < 4; ++e) {
            float p = __builtin_amdgcn_exp2f(xq[e] * 2.8853900817779268f);
            float t = 1.0f - 2.0f * __builtin_amdgcn_rcpf(p + 1.0f);
            Tk[e] = t;  t2[e] = t + t;  Tm[e] = 1.0f;
        }
#pragma unroll
        for (int kk = 0; kk < NK; ++kk) {
            bf16x4 v;
#pragma unroll
            for (int e = 0; e < 4; ++e) v[e] = (__bf16)Tk[e];
            *reinterpret_cast<bf16x4*>(wp + kk * 2048) = v;
            if (kk < NK - 1) {
#pragma unroll
                for (int e = 0; e < 4; ++e) {
                    float Tn = __builtin_fmaf(t2[e], Tk[e], -Tm[e]);
                    Tm[e] = Tk[e];  Tk[e] = Tn;
                }
            }
        }
    }
    // x(1) for the first interleaved produce
    xq = *reinterpret_cast<const f32x4*>(xp + 32);

    // B prologue: sets 0,1,2 = slabs (k=1..3, ic=0)
    bf16x8 bq[4][4];
#pragma unroll
    for (int s = 0; s < 3; ++s)
#pragma unroll
        for (int nf = 0; nf < 4; ++nf)
            bq[s][nf] = *reinterpret_cast<const bf16x8*>(
                wbase + (size_t)((s + 1) * 16) * SLAB + nf * 128);

    asm volatile("s_waitcnt lgkmcnt(0)" ::: "memory");
    __builtin_amdgcn_s_barrier();

    // produce-state registers (live across ksteps within one body)
    float Tk[4], Tm[4], t2[4];

    // BODY: consume ic from buf BUF; optionally produce ic+1 into buf 1-BUF.
    // PROD: do produce. XLOAD: load x(ic+2). PREFX: allow prefetch into ic+1.
#define BODY(BUF, IC, PROD, XLOAD, PREFX)                                        \
    {                                                                            \
        _Pragma("unroll")                                                        \
        for (int k = 1; k <= NK; ++k) {                                          \
            /* B prefetch, 3 ksteps ahead, into set (k+2)&3 */                   \
            if (k <= 5 || PREFX) {                                               \
                const int nk  = (k <= 5) ? k + 3 : k - 5;                        \
                const int nic = (k <= 5) ? (IC) : (IC) + 1;                      \
                const __bf16* np = wbase + (size_t)(nk * 16 + nic) * SLAB;       \
                _Pragma("unroll")                                                \
                for (int nf = 0; nf < 4; ++nf)                                   \
                    bq[(k + 2) & 3][nf] =                                        \
                        *reinterpret_cast<const bf16x8*>(np + nf * 128);         \
            }                                                                    \
            /* A frags from LDS (conflict-free swizzled) */                      \
            bf16x8 af[4];                                                        \
            _Pragma("unroll")                                                    \
            for (int mf = 0; mf < 4; ++mf)                                       \
                af[mf] = *reinterpret_cast<const bf16x8*>(                       \
                    abase + (BUF) * 16384 + (k - 1) * 2048 + mf * 512);          \
            /* 16 MFMA on set (k-1)&3 */                                         \
            _Pragma("unroll")                                                    \
            for (int nf = 0; nf < 4; ++nf)                                       \
                _Pragma("unroll")                                                \
                for (int mf = 0; mf < 4; ++mf)                                   \
                    acc[mf][nf] = __builtin_amdgcn_mfma_f32_16x16x32_bf16(       \
                        af[mf], bq[(k - 1) & 3][nf], acc[mf][nf], 0, 0, 0);      \
            /* interleaved produce of ic+1 into the other buffer */              \
            if (PROD) {                                                          \
                if (k == 1) {                                                    \
                    _Pragma("unroll")                                            \
                    for (int e = 0; e < 4; ++e) {                                \
                        float p = __builtin_amdgcn_exp2f(                        \
                            xq[e] * 2.8853900817779268f);                        \
                        float t = 1.0f - 2.0f * __builtin_amdgcn_rcpf(p + 1.0f); \
                        Tk[e] = t;  t2[e] = t + t;  Tm[e] = 1.0f;                \
                    }                                                            \
                } else {                                                         \
                    _Pragma("unroll")                                            \
                    for (int e = 0; e < 4; ++e) {                                \
                        float Tn = __builtin_fmaf(t2[e], Tk[e], -Tm[e]);         \
                        Tm[e] = Tk[e];  Tk[e] = Tn;                              \
                    }                                                            \
                }                                                                \
                bf16x4 v;                                                        \
                _Pragma("unroll")                                                \
                for (int e = 0; e < 4; ++e) v[e] = (__bf16)Tk[e];                \
                *reinterpret_cast<bf16x4*>(                                      \
                    wp + (1 - (BUF)) * 16384 + (k - 1) * 2048) = v;              \
            }                                                                    \
            if (XLOAD && k == 2)                                                 \
                xq = *reinterpret_cast<const f32x4*>(xp + ((IC) + 2) * 32);      \
        }                                                                        \
        if (PROD) {                                                              \
            asm volatile("s_waitcnt lgkmcnt(0)" ::: "memory");                   \
            __builtin_amdgcn_s_barrier();                                        \
        }                                                                        \
    }

    // main: ic = 0..13 (full pipeline; x(ic+2) <= x(15) always valid)
    for (int icp = 0; icp < 14; icp += 2) {
        BODY(0, icp,     1, 1, 1);
        BODY(1, icp + 1, 1, 1, 1);
    }
    // tail: ic=14 (produce 15, no x-load), ic=15 (drain)
    BODY(0, 14, 1, 0, 1);
    BODY(1, 15, 0, 0, 0);
#undef BODY

    // ---- epilogue: C/D layout col=lane&15, row=(lane>>4)*4+r ----
#pragma unroll
    for (int mf = 0; mf < 4; ++mf)
#pragma unroll
        for (int r = 0; r < 4; ++r) {
            const int row = bm + mf * 16 + l4 * 4 + r;
            float* orow = out + (size_t)row * DIM + wid * 64 + l15;
#pragma unroll
            for (int nf = 0; nf < 4; ++nf)
                orow[nf * 16] = acc[mf][nf][r];
        }
}

extern "C" void kernel_launch(void* const* d_in, const int* in_sizes, int n_in,
                              void* d_out, int out_size, void* d_ws, size_t ws_size,
                              hipStream_t stream) {
    const float* x      = (const float*)d_in[0];   // (16384, 512)
    const float* coeffs = (const float*)d_in[1];   // (512, 512, 9)
    float* out          = (float*)d_out;           // (16384, 512)
    __bf16* W2          = (__bf16*)d_ws;           // 144*16384 bf16 = 4.7MB

    pack_w_kernel<<<(DIM * 64) / 256, 256, 0, stream>>>(coeffs, W2);
    s0_kernel<<<DIM, 64, 0, stream>>>(coeffs, (float*)W2);

    // grid = M/64 = 256 blocks of 512 thr = 1 block/CU, 2 waves/SIMD.
    cheby_gemm_kernel<<<256, 512, 0, stream>>>(x, W2, out);
}

// Round 15
// 80.119 us; speedup vs baseline: 1.4655x; 1.1589x over previous
//
#include <hip/hip_runtime.h>
#include <hip/hip_bf16.h>

// ChebyKANLinear: y[b,j] = sum_i sum_k T_k(tanh(x[b,i])) * C[i,j,k]
// GEMM: M=16384, N=512, K=4608 (kflat = k*512 + i), k=0 folded into S0[j].
// v14 = v13's interleaved produce/consume + XCD-parity N-split:
//   nhalf = bid&1 and XCD = bid%8  =>  every block on an XCD reads the SAME
//   2.36MB half of W2 -> fully L2-resident (v13 diagnosis: 4.7MB W2 thrashed
//   the 4MB XCD L2; B stream fell to L3 at ~20 B/cyc = the measured 1613
//   cyc/kstep). Cost: basis dup=2, x fetched twice - both far under ceilings.
//   Geometry: 512-thr blocks, BM=64, BN=256, wave tile 64x32, grid 512 =
//   2 blocks/CU = 4 waves/SIMD (~120 regs); co-resident blocks share nhalf
//   so block 2's B-reads L1-hit. 4-set depth-3 B prefetch, 1 barrier/ic.

typedef __bf16 bf16x8 __attribute__((ext_vector_type(8)));
typedef __bf16 bf16x4 __attribute__((ext_vector_type(4)));
typedef float  f32x4  __attribute__((ext_vector_type(4)));

#define DIM  512
#define KDEG 9
#define NK   8               // k = 1..8 (k=0 folded into S0)
#define NIC  16
#define SLAB (4 * DIM * 8)   // 16384 bf16 per (k,ic) slab of W2

// ---- pack: C[i][j][k] -> W2[(k*16+ic)][s][j][e] (bf16), i = ic*32 + s*8 + e ----
__global__ void pack_w_kernel(const float* __restrict__ coeffs,
                              __bf16* __restrict__ W2) {
    int t  = blockIdx.x * blockDim.x + threadIdx.x;   // 32768 threads
    int j  = t & (DIM - 1);
    int s  = (t >> 9) & 3;
    int ic = t >> 11;

    bf16x8 v[KDEG];
#pragma unroll
    for (int e = 0; e < 8; ++e) {
        int i = ic * 32 + s * 8 + e;
        const float* src = coeffs + ((size_t)i * DIM + j) * KDEG;
#pragma unroll
        for (int k = 0; k < KDEG; ++k)
            v[k][e] = (__bf16)src[k];
    }
#pragma unroll
    for (int k = 0; k < KDEG; ++k) {
        size_t off = (size_t)(k * 16 + ic) * SLAB + ((size_t)s * DIM + j) * 8;
        *reinterpret_cast<bf16x8*>(W2 + off) = v[k];
    }
}

// ---- S0[j] = sum_i C[i][j][0] (f32) into W2's k=0 slab (GEMM never reads it) ----
__global__ void s0_kernel(const float* __restrict__ coeffs,
                          float* __restrict__ S0) {
    const int j    = blockIdx.x;      // 512 blocks
    const int lane = threadIdx.x;     // 64
    float s = 0.0f;
#pragma unroll
    for (int i = lane; i < DIM; i += 64)
        s += coeffs[((size_t)i * DIM + j) * KDEG];
#pragma unroll
    for (int off = 32; off > 0; off >>= 1)
        s += __shfl_down(s, off, 64);
    if (lane == 0) S0[j] = s;
}

// ---------------- fused GEMM: consume(ic) with produce(ic+1) interleaved --------
__global__ __launch_bounds__(512, 4) void cheby_gemm_kernel(
    const float* __restrict__ x,
    const __bf16* __restrict__ W2,
    float* __restrict__ out)
{
    // double-buffered A-tile: [buf][kk][row(64)][slot(4)][8] bf16, 2 x 32KB
    __shared__ __bf16 A_lds[2][NK][64][4][8];

    const int tid   = threadIdx.x;
    const int lane  = tid & 63;
    const int wid   = tid >> 6;      // 0..7 = n-group (32 cols each)
    const int l15   = lane & 15;
    const int l4    = lane >> 4;     // 0..3
    const int nhalf = blockIdx.x & 1;            // == XCD parity (XCD = bid%8)
    const int bm    = (blockIdx.x >> 1) * 64;
    const int cb    = nhalf * 256 + wid * 32;    // wave's column base

    // ---- producer mapping (v12-verified): thread owns 4 consecutive i ----
    const int prow  = tid >> 3;           // 0..63
    const int pi4   = (tid & 7) * 4;      // 0,4,...,28
    const int pslot = pi4 >> 3;           // 0..3
    const int phalf = (pi4 >> 2) & 1;     // 8B half within slot
    const int rsw   = (prow >> 1) & 3;    // row-pair slot swizzle
    __bf16* wp = &A_lds[0][0][prow][pslot ^ rsw][phalf * 4];
    const float* xp = x + (size_t)(bm + prow) * DIM + pi4;

    // ---- consumer A read base: row = mf*16 + l15, logical slot l4 ----
    const __bf16* abase = &A_lds[0][0][l15][l4 ^ ((l15 >> 1) & 3)][0];

    // ---- B lane base: granule (l4*DIM + cb + nf*16 + l15), 16B each ----
    const __bf16* wbase = W2 + ((size_t)l4 * DIM + cb + l15) * 8;

    // acc init from S0 (the k=0 term)
    const float* S0 = (const float*)W2;
    f32x4 acc[4][2];
#pragma unroll
    for (int nf = 0; nf < 2; ++nf) {
        float s0v = S0[cb + nf * 16 + l15];
#pragma unroll
        for (int mf = 0; mf < 4; ++mf)
#pragma unroll
            for (int r = 0; r < 4; ++r)
                acc[mf][nf][r] = s0v;
    }

    // ================= prologue =================
    // x(0); produce ic=0 into buf 0 (serial, once)
    f32x4 xq = *reinterpret_cast<const f32x4*>(xp);
    {
        float Tk[4], Tm[4], t2[4];
#pragma unroll
        for (int e = 0; e < 4; ++e) {
            float p = __builtin_amdgcn_exp2f(xq[e] * 2.8853900817779268f);
            float t = 1.0f - 2.0f * __builtin_amdgcn_rcpf(p + 1.0f);
            Tk[e] = t;  t2[e] = t + t;  Tm[e] = 1.0f;
        }
#pragma unroll
        for (int kk = 0; kk < NK; ++kk) {
            bf16x4 v;
#pragma unroll
            for (int e = 0; e < 4; ++e) v[e] = (__bf16)Tk[e];
            *reinterpret_cast<bf16x4*>(wp + kk * 2048) = v;
            if (kk < NK - 1) {
#pragma unroll
                for (int e = 0; e < 4; ++e) {
                    float Tn = __builtin_fmaf(t2[e], Tk[e], -Tm[e]);
                    Tm[e] = Tk[e];  Tk[e] = Tn;
                }
            }
        }
    }
    // x(1) for the first interleaved produce
    xq = *reinterpret_cast<const f32x4*>(xp + 32);

    // B prologue: sets 0,1,2 = slabs (k=1..3, ic=0)
    bf16x8 bq[4][2];
#pragma unroll
    for (int s = 0; s < 3; ++s)
#pragma unroll
        for (int nf = 0; nf < 2; ++nf)
            bq[s][nf] = *reinterpret_cast<const bf16x8*>(
                wbase + (size_t)((s + 1) * 16) * SLAB + nf * 128);

    asm volatile("s_waitcnt lgkmcnt(0)" ::: "memory");
    __builtin_amdgcn_s_barrier();

    // produce-state registers (live across ksteps within one body)
    float Tk[4], Tm[4], t2[4];

    // BODY: consume ic from buf BUF; optionally produce ic+1 into buf 1-BUF.
#define BODY(BUF, IC, PROD, XLOAD, PREFX)                                        \
    {                                                                            \
        _Pragma("unroll")                                                        \
        for (int k = 1; k <= NK; ++k) {                                          \
            /* B prefetch, 3 ksteps ahead, into set (k+2)&3 */                   \
            if (k <= 5 || PREFX) {                                               \
                const int nk  = (k <= 5) ? k + 3 : k - 5;                        \
                const int nic = (k <= 5) ? (IC) : (IC) + 1;                      \
                const __bf16* np = wbase + (size_t)(nk * 16 + nic) * SLAB;       \
                _Pragma("unroll")                                                \
                for (int nf = 0; nf < 2; ++nf)                                   \
                    bq[(k + 2) & 3][nf] =                                        \
                        *reinterpret_cast<const bf16x8*>(np + nf * 128);         \
            }                                                                    \
            /* A frags from LDS (conflict-free swizzled) */                      \
            bf16x8 af[4];                                                        \
            _Pragma("unroll")                                                    \
            for (int mf = 0; mf < 4; ++mf)                                       \
                af[mf] = *reinterpret_cast<const bf16x8*>(                       \
                    abase + (BUF) * 16384 + (k - 1) * 2048 + mf * 512);          \
            /* 8 MFMA on set (k-1)&3 */                                          \
            _Pragma("unroll")                                                    \
            for (int nf = 0; nf < 2; ++nf)                                       \
                _Pragma("unroll")                                                \
                for (int mf = 0; mf < 4; ++mf)                                   \
                    acc[mf][nf] = __builtin_amdgcn_mfma_f32_16x16x32_bf16(       \
                        af[mf], bq[(k - 1) & 3][nf], acc[mf][nf], 0, 0, 0);      \
            /* interleaved produce of ic+1 into the other buffer */              \
            if (PROD) {                                                          \
                if (k == 1) {                                                    \
                    _Pragma("unroll")                                            \
                    for (int e = 0; e < 4; ++e) {                                \
                        float p = __builtin_amdgcn_exp2f(                        \
                            xq[e] * 2.8853900817779268f);                        \
                        float t = 1.0f - 2.0f * __builtin_amdgcn_rcpf(p + 1.0f); \
                        Tk[e] = t;  t2[e] = t + t;  Tm[e] = 1.0f;                \
                    }                                                            \
                } else {                                                         \
                    _Pragma("unroll")                                            \
                    for (int e = 0; e < 4; ++e) {                                \
                        float Tn = __builtin_fmaf(t2[e], Tk[e], -Tm[e]);         \
                        Tm[e] = Tk[e];  Tk[e] = Tn;                              \
                    }                                                            \
                }                                                                \
                bf16x4 v;                                                        \
                _Pragma("unroll")                                                \
                for (int e = 0; e < 4; ++e) v[e] = (__bf16)Tk[e];                \
                *reinterpret_cast<bf16x4*>(                                      \
                    wp + (1 - (BUF)) * 16384 + (k - 1) * 2048) = v;              \
            }                                                                    \
            if (XLOAD && k == 2)                                                 \
                xq = *reinterpret_cast<const f32x4*>(xp + ((IC) + 2) * 32);      \
        }                                                                        \
        if (PROD) {                                                              \
            asm volatile("s_waitcnt lgkmcnt(0)" ::: "memory");                   \
            __builtin_amdgcn_s_barrier();                                        \
        }                                                                        \
    }

    // main: ic = 0..13 (full pipeline; x(ic+2) <= x(15) always valid)
    for (int icp = 0; icp < 14; icp += 2) {
        BODY(0, icp,     1, 1, 1);
        BODY(1, icp + 1, 1, 1, 1);
    }
    // tail: ic=14 (produce 15, no x-load), ic=15 (drain)
    BODY(0, 14, 1, 0, 1);
    BODY(1, 15, 0, 0, 0);
#undef BODY

    // ---- epilogue: C/D layout col=lane&15, row=(lane>>4)*4+r ----
#pragma unroll
    for (int mf = 0; mf < 4; ++mf)
#pragma unroll
        for (int r = 0; r < 4; ++r) {
            const int row = bm + mf * 16 + l4 * 4 + r;
            float* orow = out + (size_t)row * DIM + cb + l15;
#pragma unroll
            for (int nf = 0; nf < 2; ++nf)
                orow[nf * 16] = acc[mf][nf][r];
        }
}

extern "C" void kernel_launch(void* const* d_in, const int* in_sizes, int n_in,
                              void* d_out, int out_size, void* d_ws, size_t ws_size,
                              hipStream_t stream) {
    const float* x      = (const float*)d_in[0];   // (16384, 512)
    const float* coeffs = (const float*)d_in[1];   // (512, 512, 9)
    float* out          = (float*)d_out;           // (16384, 512)
    __bf16* W2          = (__bf16*)d_ws;           // 144*16384 bf16 = 4.7MB

    pack_w_kernel<<<(DIM * 64) / 256, 256, 0, stream>>>(coeffs, W2);
    s0_kernel<<<DIM, 64, 0, stream>>>(coeffs, (float*)W2);

    // grid = 2 n-halves x 256 m-blocks = 512 blocks of 512 thr = 2 blocks/CU
    // = 4 waves/SIMD. nhalf = bid&1 matches XCD parity (XCD = bid%8) -> each
    // XCD L2 holds one 2.36MB W2 half, fully resident.
    cheby_gemm_kernel<<<512, 512, 0, stream>>>(x, W2, out);
}